// Round 8
// baseline (383.567 us; speedup 1.0000x reference)
//
#include <hip/hip_runtime.h>

#define U_   8
#define B_   16384
#define NC_  62

typedef __attribute__((ext_vector_type(8))) short bfrag;   // 8 bf16 (4 VGPRs)
typedef __attribute__((ext_vector_type(4))) float facc;    // 4 fp32 acc

__device__ __forceinline__ float bf2f(unsigned int lo16) {
    union { unsigned int i; float f; } v;
    v.i = lo16 << 16;
    return v.f;
}
__device__ __forceinline__ unsigned short f2bf(float f) {
    unsigned int x = __float_as_uint(f);
    return (unsigned short)((x + 0x7fffu + ((x >> 16) & 1u)) >> 16);
}
__device__ __forceinline__ void gl2lds16(const void* g, void* l) {
    __builtin_amdgcn_global_load_lds(
        (const __attribute__((address_space(1))) void*)g,
        (__attribute__((address_space(3))) void*)l, 16, 0, 0);
}
// compiler-level fence: pins issue order of memory ops (no HW cost)
__device__ __forceinline__ void cfence() { asm volatile("" ::: "memory"); }
// plain raw barrier (no counter drain) — only where no LDS WAR follows
__device__ __forceinline__ void bar() {
    asm volatile("" ::: "memory");
    __builtin_amdgcn_s_barrier();
    asm volatile("" ::: "memory");
}
// recycle barrier: drain lgkmcnt so this wave's ds_reads are IN REGISTERS
// before anyone overwrites the LDS buffer (rule-#18 hazard). vmcnt NOT drained.
__device__ __forceinline__ void barL() {
    asm volatile("s_waitcnt lgkmcnt(0)" ::: "memory");
    __builtin_amdgcn_s_barrier();
    asm volatile("" ::: "memory");
}
#define VMCNT(n) asm volatile("s_waitcnt vmcnt(" #n ")" ::: "memory")

// ---------------------------------------------------------------------------
// prep: normalized policies, final per-unit weights, folded output bias
// ---------------------------------------------------------------------------
__global__ void prep_kernel(const float* __restrict__ p1, const float* __restrict__ p2,
                            const float* __restrict__ pf, const float* __restrict__ b2,
                            float* __restrict__ P1n, float* __restrict__ P2n,
                            float* __restrict__ wfin, float* __restrict__ cconst)
{
    int t = threadIdx.x;
    if (t >= 64) return;
    int row = t >> 3;
    float s1 = 0.f, s2 = 0.f;
    for (int f = 0; f < 8; f++) { s1 += p1[row * 8 + f]; s2 += p2[row * 8 + f]; }
    P1n[t] = p1[t] * (s1 > 0.f ? 1.f / s1 : 1.f);
    P2n[t] = p2[t] * (s2 > 0.f ? 1.f / s2 : 1.f);
    float d = 0.f;
    for (int j = 0; j < 8; j++) d += pf[j];
    float inv = d > 0.f ? 1.f / d : 1.f;
    float wv[8];
    for (int j = 0; j < 8; j++) {
        float v = pf[j];
        for (int i = j; i < 8; i++) v *= inv;   // inv applied (8-j) times
        wv[j] = v;
    }
    if (t < 8) wfin[t] = wv[t];
    float cc = 0.f;
    if (t < NC_) for (int u = 0; u < 8; u++) cc += wv[u] * b2[u * NC_ + t];
    cconst[t] = cc;
}

// ---------------------------------------------------------------------------
// reorder_w0: W0 [u][k=512][n=512] fp32 -> W0r[n'][k] bf16,
//             n' = (n>>5)*256 + u*32 + (n&31)   (256-col groups: 8u x 32f)
// ---------------------------------------------------------------------------
__global__ __launch_bounds__(256) void reorder_w0(
    const float* __restrict__ W0, unsigned short* __restrict__ W0r)
{
    __shared__ float tile[32][33];
    const int u  = blockIdx.z;
    const int n0 = blockIdx.x * 32, k0 = blockIdx.y * 32;
    const int tx = threadIdx.x & 31, ty = threadIdx.x >> 5;
    const float* Wb = W0 + (long)u * 512 * 512;
#pragma unroll
    for (int i = 0; i < 4; i++)
        tile[ty + i * 8][tx] = Wb[(long)(k0 + ty + i * 8) * 512 + n0 + tx];
    __syncthreads();
#pragma unroll
    for (int i = 0; i < 4; i++) {
        int n = n0 + ty + i * 8, k = k0 + tx;
        int np = (n >> 5) * 256 + u * 32 + (n & 31);
        W0r[(long)np * 512 + k] = f2bf(tile[tx][ty + i * 8]);
    }
}

// ---------------------------------------------------------------------------
// transpose_w: W [u][k=512][n=512] fp32 -> Wt [u][n][k] bf16
// ---------------------------------------------------------------------------
__global__ __launch_bounds__(256) void transpose_w(
    const float* __restrict__ W, unsigned short* __restrict__ Wt)
{
    __shared__ float tile[32][33];
    const int u  = blockIdx.z;
    const int n0 = blockIdx.x * 32, k0 = blockIdx.y * 32;
    const int tx = threadIdx.x & 31, ty = threadIdx.x >> 5;
    const float* Wb = W + (long)u * 512 * 512;
#pragma unroll
    for (int i = 0; i < 4; i++)
        tile[ty + i * 8][tx] = Wb[(long)(k0 + ty + i * 8) * 512 + n0 + tx];
    __syncthreads();
    unsigned short* Wo = Wt + (long)u * 512 * 512;
#pragma unroll
    for (int i = 0; i < 4; i++) {
        int n = n0 + ty + i * 8, k = k0 + tx;
        Wo[(long)n * 512 + k] = f2bf(tile[tx][ty + i * 8]);
    }
}

// ---------------------------------------------------------------------------
// wout_build: Woutt[c][f*512+k] = sum_u wfin[u]*P2n[u,f]*W2[u][k][c]  (c<62)
// ---------------------------------------------------------------------------
__global__ __launch_bounds__(256) void wout_build(
    const float* __restrict__ W2, const float* __restrict__ P2n,
    const float* __restrict__ wfin, unsigned short* __restrict__ Woutt)
{
    const int c   = threadIdx.x & 63;
    const int row = blockIdx.x * 4 + (threadIdx.x >> 6);   // [0,4096)
    const int f = row >> 9, k = row & 511;
    float s = 0.f;
    if (c < NC_) {
#pragma unroll
        for (int u = 0; u < 8; u++)
            s += wfin[u] * P2n[u * 8 + f] * W2[((long)u * 512 + k) * NC_ + c];
    }
    Woutt[(long)c * 4096 + row] = f2bf(s);
}

// ---------------------------------------------------------------------------
// x fp32 -> bf16, 8 elems/thread
// ---------------------------------------------------------------------------
__global__ __launch_bounds__(256) void convert_x(
    const float* __restrict__ x, unsigned short* __restrict__ xb, long n)
{
    long i = ((long)blockIdx.x * 256 + threadIdx.x) * 8;
    if (i >= n) return;
    const float4* xp = (const float4*)(x + i);
    float4 a = xp[0], b = xp[1];
    uint4 o;
    o.x = f2bf(a.x) | ((unsigned)f2bf(a.y) << 16);
    o.y = f2bf(a.z) | ((unsigned)f2bf(a.w) << 16);
    o.z = f2bf(b.x) | ((unsigned)f2bf(b.y) << 16);
    o.w = f2bf(b.z) | ((unsigned)f2bf(b.w) << 16);
    *(uint4*)(xb + i) = o;
}

// ---------------------------------------------------------------------------
// gemm0_mix v8 (= v7 kernel, L3-chunked launch): 256 thr / 4 waves 2x2,
// 128 rows x 256 cols, BK=32, dbuf + barL + counted vmcnt, SLAB a1 output
// a1[(t*16+ng)*Bc + row][32] (full-line contiguous 8 KB per plane/block).
// ---------------------------------------------------------------------------
__global__ __launch_bounds__(256, 2) void gemm0_mix(
    const unsigned short* __restrict__ xb, const unsigned short* __restrict__ W0r,
    const float* __restrict__ b0, const float* __restrict__ P1n,
    unsigned short* __restrict__ a1, long plane)
{
    __shared__ __align__(16) unsigned short sm[33792];   // 67584 B
    const int tid = threadIdx.x, w = tid >> 6, lane = tid & 63;
    const int flat = blockIdx.x;
    const int xcd = flat & 7, seq = flat >> 3;
    const int ng = xcd * 2 + (seq & 1);           // 2 n-groups per XCD
    const long mBase = (long)(seq >> 1) * 128;
    const long Bc = plane >> 9;                   // rows per chunk

    const int lr = lane >> 2;                          // row within 16-row chunk
    const int lg = (lane & 3) ^ ((lane >> 3) & 3);     // swizzled source granule
    const int wm = w >> 1, wn = w & 1;
    const int r = lane & 15, q = lane >> 4;
    const int xq = (q ^ ((r >> 1) & 3)) * 8;           // per-lane read slot offset

    facc acc[4][8];
#pragma unroll
    for (int i = 0; i < 4; i++)
#pragma unroll
        for (int j = 0; j < 8; j++) acc[i][j] = (facc){0.f, 0.f, 0.f, 0.f};

    auto stage = [&](int buf, int kt) {               // 6 gl2lds per wave
        const int k0 = kt * 32;
        unsigned short* dA = sm + buf * 4096;                 // [128][32]
        unsigned short* dB = sm + 8192 + buf * 8192;          // [256][32]
#pragma unroll
        for (int i = 0; i < 2; i++) {
            const int c = w * 2 + i;                          // 8 A-chunks
            gl2lds16(xb + (mBase + c * 16 + lr) * 512 + k0 + lg * 8, dA + c * 512);
        }
#pragma unroll
        for (int i = 0; i < 4; i++) {
            const int c = w * 4 + i;                          // 16 B-chunks
            gl2lds16(W0r + ((long)ng * 256 + c * 16 + lr) * 512 + k0 + lg * 8,
                     dB + c * 512);
        }
    };
    auto compute = [&](int buf) {
        const unsigned short* sA = sm + buf * 4096;
        const unsigned short* sB = sm + 8192 + buf * 8192;
        bfrag aF[4], bF[8];
#pragma unroll
        for (int mt = 0; mt < 4; mt++)
            aF[mt] = *(const bfrag*)&sA[(wm * 64 + mt * 16 + r) * 32 + xq];
#pragma unroll
        for (int nt = 0; nt < 8; nt++)
            bF[nt] = *(const bfrag*)&sB[(wn * 128 + nt * 16 + r) * 32 + xq];
#pragma unroll
        for (int mt = 0; mt < 4; mt++)
#pragma unroll
            for (int nt = 0; nt < 8; nt++)
                acc[mt][nt] = __builtin_amdgcn_mfma_f32_16x16x32_bf16(
                    aF[mt], bF[nt], acc[mt][nt], 0, 0, 0);
    };

    stage(0, 0);
    cfence();            // pin issue groups so vmcnt counting is exact
    stage(1, 1);
    VMCNT(6);            // kt0's 6 loads done (kt1's 6 still in flight)
    bar();
#pragma unroll
    for (int t = 0; t < 16; ++t) {
        compute(t & 1);
        if (t <= 13) {
            barL();                    // ds_reads of buf t&1 in regs, all waves
            stage(t & 1, t + 2);       // refill it for iter t+2
            VMCNT(6);                  // loads for iter t+1 complete
            bar();
        } else if (t == 14) {
            VMCNT(0);                  // drain kt15 loads
            bar();
        } else {
            barL();                    // epilogue overwrites LDS next
        }
    }

    // epilogue: acc -> sm as h0 tile [128 rows][264]
#pragma unroll
    for (int nt = 0; nt < 8; nt++) {
        const int cl = wn * 128 + nt * 16 + r;     // u = cl>>5, f = cl&31
        const float bv = b0[(cl >> 5) * 512 + ng * 32 + (cl & 31)];
#pragma unroll
        for (int mt = 0; mt < 4; mt++) {
            const int rowb = wm * 64 + mt * 16 + q * 4;
#pragma unroll
            for (int rg = 0; rg < 4; rg++) {
                float v = acc[mt][nt][rg] + bv;
                v = v > 0.f ? v : 0.f;
                sm[(rowb + rg) * 264 + cl] = f2bf(v);
            }
        }
    }
    __syncthreads();

    // mix: thread -> (row = tid>>1, fs0 = (tid&1)*16); SLAB stores
    float pw[64];
#pragma unroll
    for (int i = 0; i < 64; i++) pw[i] = P1n[i];   // uniform -> SGPRs
    const int row = tid >> 1, fs0 = (tid & 1) * 16;
    float hv[8][16];
#pragma unroll
    for (int u = 0; u < 8; u++) {
        bfrag ha = *(const bfrag*)&sm[row * 264 + u * 32 + fs0];
        bfrag hb = *(const bfrag*)&sm[row * 264 + u * 32 + fs0 + 8];
#pragma unroll
        for (int j = 0; j < 8; j++) {
            hv[u][j]     = bf2f((unsigned int)(unsigned short)ha[j]);
            hv[u][j + 8] = bf2f((unsigned int)(unsigned short)hb[j]);
        }
    }
#pragma unroll
    for (int t = 0; t < 8; t++) {
        float o[16];
#pragma unroll
        for (int j = 0; j < 16; j++) {
            float s = 0.f;
#pragma unroll
            for (int u = 0; u < 8; u++) s = fmaf(pw[t * 8 + u], hv[u][j], s);
            o[j] = s;
        }
        uint4 ov0, ov1;
        ov0.x = f2bf(o[0])  | ((unsigned)f2bf(o[1])  << 16);
        ov0.y = f2bf(o[2])  | ((unsigned)f2bf(o[3])  << 16);
        ov0.z = f2bf(o[4])  | ((unsigned)f2bf(o[5])  << 16);
        ov0.w = f2bf(o[6])  | ((unsigned)f2bf(o[7])  << 16);
        ov1.x = f2bf(o[8])  | ((unsigned)f2bf(o[9])  << 16);
        ov1.y = f2bf(o[10]) | ((unsigned)f2bf(o[11]) << 16);
        ov1.z = f2bf(o[12]) | ((unsigned)f2bf(o[13]) << 16);
        ov1.w = f2bf(o[14]) | ((unsigned)f2bf(o[15]) << 16);
        unsigned short* dst = a1 + (((long)t * 16 + ng) * Bc + mBase + row) * 32 + fs0;
        *(uint4*)(dst)     = ov0;
        *(uint4*)(dst + 8) = ov1;
    }
}

// ---------------------------------------------------------------------------
// gemm_h v8 (= v7): 128x128 tile, 256 thr / 4 waves, BK=32, dbuf + barL +
// VMCNT(4). A from a1 SLABS (contiguous); B from W1t. LDS 34816 B.
// ---------------------------------------------------------------------------
__global__ __launch_bounds__(256, 2) void gemm_h(
    const unsigned short* __restrict__ a1,     // slab [u][16][Bc][32]
    const unsigned short* __restrict__ W1t,    // [u][n][k]
    const float* __restrict__ b1,
    unsigned short* __restrict__ h1, long plane)
{
    __shared__ __align__(16) unsigned short sm[17408];   // 34816 B
    const int tid = threadIdx.x, w = tid >> 6, lane = tid & 63;
    const int flat = blockIdx.x;
    const int u = flat & 7, seq = flat >> 3;             // xcd = u
    const int nBase = (seq & 3) * 128;
    const long mBase = (long)(seq >> 2) * 128;
    const long Bc = plane >> 9;

    const int lr = lane >> 2;
    const int lg = (lane & 3) ^ ((lane >> 3) & 3);
    const int wm = w >> 1, wn = w & 1;
    const int r = lane & 15, q = lane >> 4;
    const int xq = (q ^ ((r >> 1) & 3)) * 8;

    const unsigned short* Bb = W1t + ((long)u * 512 + nBase) * 512;

    facc acc[4][4];
#pragma unroll
    for (int i = 0; i < 4; i++)
#pragma unroll
        for (int j = 0; j < 4; j++) acc[i][j] = (facc){0.f, 0.f, 0.f, 0.f};

    auto stage = [&](int buf, int kt) {               // 4 gl2lds per wave
        unsigned short* dA = sm + buf * 4096;                 // [128][32]
        unsigned short* dB = sm + 8192 + buf * 4096;          // [128][32]
        const unsigned short* As = a1 + (((long)u * 16 + kt) * Bc + mBase) * 32;
#pragma unroll
        for (int i = 0; i < 2; i++) {
            const int c = w * 2 + i;                          // 8 A-chunks
            gl2lds16(As + (c * 16 + lr) * 32 + lg * 8, dA + c * 512);
        }
#pragma unroll
        for (int i = 0; i < 2; i++) {
            const int c = w * 2 + i;                          // 8 B-chunks
            gl2lds16(Bb + (long)(c * 16 + lr) * 512 + kt * 32 + lg * 8,
                     dB + c * 512);
        }
    };
    auto compute = [&](int buf) {
        const unsigned short* sA = sm + buf * 4096;
        const unsigned short* sB = sm + 8192 + buf * 4096;
        bfrag aF[4], bF[4];
#pragma unroll
        for (int mt = 0; mt < 4; mt++)
            aF[mt] = *(const bfrag*)&sA[(wm * 64 + mt * 16 + r) * 32 + xq];
#pragma unroll
        for (int nt = 0; nt < 4; nt++)
            bF[nt] = *(const bfrag*)&sB[(wn * 64 + nt * 16 + r) * 32 + xq];
#pragma unroll
        for (int mt = 0; mt < 4; mt++)
#pragma unroll
            for (int nt = 0; nt < 4; nt++)
                acc[mt][nt] = __builtin_amdgcn_mfma_f32_16x16x32_bf16(
                    aF[mt], bF[nt], acc[mt][nt], 0, 0, 0);
    };

    stage(0, 0);
    cfence();
    stage(1, 1);
    VMCNT(4);
    bar();
#pragma unroll
    for (int t = 0; t < 16; ++t) {
        compute(t & 1);
        if (t <= 13) {
            barL();
            stage(t & 1, t + 2);
            VMCNT(4);
            bar();
        } else if (t == 14) {
            VMCNT(0);
            bar();
        } else {
            barL();
        }
    }

    // epilogue: acc -> sm as C tile [128][136]
#pragma unroll
    for (int nt = 0; nt < 4; nt++) {
        const int col = wn * 64 + nt * 16 + r;
        const float bv = b1[u * 512 + nBase + col];
#pragma unroll
        for (int mt = 0; mt < 4; mt++) {
            const int rowb = wm * 64 + mt * 16 + q * 4;
#pragma unroll
            for (int rg = 0; rg < 4; rg++) {
                float v = acc[mt][nt][rg] + bv;
                v = v > 0.f ? v : 0.f;
                sm[(rowb + rg) * 136 + col] = f2bf(v);
            }
        }
    }
    __syncthreads();

    // coalesced write: 16 lanes x 16 B = 256-B full row runs
    unsigned short* Cb = h1 + (long)u * plane + mBase * 512 + nBase;
#pragma unroll
    for (int it = 0; it < 8; it++) {
        const int g = tid + it * 256;
        const int row = g >> 4, gr = g & 15;
        *(uint4*)(Cb + (long)row * 512 + gr * 8) = *(const uint4*)&sm[row * 136 + gr * 8];
    }
}

// ---------------------------------------------------------------------------
// gemm_out v8: split-K=4 (kc over 2 h1-planes each, 16 k-iters), 64x64 tile,
// BK=64, dbuf + counted vmcnt + barL, xor-swizzle, fp32 partial.
// Grid = 4 x (Bc/64) -> 256 blocks at Bc=4096.  LDS = 32 KB.
// ---------------------------------------------------------------------------
__global__ __launch_bounds__(256, 1) void gemm_out(
    const unsigned short* __restrict__ h1,     // planar [f][rows][512]
    const unsigned short* __restrict__ Bt,     // Woutt [64 c][4096]
    float* __restrict__ partial, long plane, int Bc)
{
    __shared__ __align__(16) unsigned short sm[16384];   // 32768 B
    const int tid = threadIdx.x, w = tid >> 6, lane = tid & 63;
    const int flat = blockIdx.x;
    const int kc = flat & 3;
    const long mBase = (long)(flat >> 2) * 64;

    const int lr = lane >> 3, lg = (lane & 7) ^ lr;
    const int wm = w >> 1, wn = w & 1;
    const int r = lane & 15, q = lane >> 4;
    const int x7 = r & 7;

    facc acc[2][2];
#pragma unroll
    for (int i = 0; i < 2; i++)
#pragma unroll
        for (int j = 0; j < 2; j++) acc[i][j] = (facc){0.f, 0.f, 0.f, 0.f};

    auto stage = [&](int buf, int it) {               // 4 gl2lds per wave
        const int u = kc * 2 + (it >> 3);
        const int kk = (it & 7) * 64;
        unsigned short* dA = sm + buf * 4096;
        unsigned short* dB = sm + 8192 + buf * 4096;
#pragma unroll
        for (int i = 0; i < 2; i++) {
            const int c = w * 2 + i;
            gl2lds16(h1 + (long)u * plane + (mBase + c * 8 + lr) * 512 + kk + lg * 8,
                     dA + c * 512);
            gl2lds16(Bt + (long)(c * 8 + lr) * 4096 + u * 512 + kk + lg * 8,
                     dB + c * 512);
        }
    };
    auto compute = [&](int buf) {
        const unsigned short* sA = sm + buf * 4096;
        const unsigned short* sB = sm + 8192 + buf * 4096;
#pragma unroll
        for (int h = 0; h < 2; h++) {
            const int xg = ((h * 4 + q) ^ x7) * 8;
            bfrag aF[2], bF[2];
#pragma unroll
            for (int mt = 0; mt < 2; mt++)
                aF[mt] = *(const bfrag*)&sA[(wm * 32 + mt * 16 + r) * 64 + xg];
#pragma unroll
            for (int nt = 0; nt < 2; nt++)
                bF[nt] = *(const bfrag*)&sB[(wn * 32 + nt * 16 + r) * 64 + xg];
#pragma unroll
            for (int mt = 0; mt < 2; mt++)
#pragma unroll
                for (int nt = 0; nt < 2; nt++)
                    acc[mt][nt] = __builtin_amdgcn_mfma_f32_16x16x32_bf16(
                        aF[mt], bF[nt], acc[mt][nt], 0, 0, 0);
        }
    };

    stage(0, 0);
    cfence();            // pin issue groups
    stage(1, 1);
    VMCNT(4);
    bar();
#pragma unroll
    for (int t = 0; t < 16; ++t) {
        compute(t & 1);
        if (t <= 13) {
            barL();
            stage(t & 1, t + 2);
            VMCNT(4);
            bar();
        } else if (t == 14) {
            VMCNT(0);
            bar();
        }
        // t == 15: no LDS reuse afterwards, registers go straight to global
    }

    float* pb = partial + ((long)kc * Bc + mBase) * 64;
#pragma unroll
    for (int nt = 0; nt < 2; nt++) {
        const int col = wn * 32 + nt * 16 + r;
#pragma unroll
        for (int mt = 0; mt < 2; mt++) {
#pragma unroll
            for (int rg = 0; rg < 4; rg++) {
                const int row = wm * 32 + mt * 16 + q * 4 + rg;
                pb[(long)row * 64 + col] = acc[mt][nt][rg];
            }
        }
    }
}

// ---------------------------------------------------------------------------
// reduce_out: out[row][c] = sum_kc partial[kc] + cconst[c]   (4 partials)
// ---------------------------------------------------------------------------
__global__ __launch_bounds__(256) void reduce_out(
    const float* __restrict__ partial, const float* __restrict__ cconst,
    float* __restrict__ out, int Bc)
{
    const long flat = (long)blockIdx.x * 256 + threadIdx.x;
    const long row = flat >> 2;
    const int cg = (int)(flat & 3) * 16;
    float s[16];
#pragma unroll
    for (int j = 0; j < 16; j++) s[j] = 0.f;
#pragma unroll
    for (int kc = 0; kc < 4; kc++) {
        const float4* p = (const float4*)(partial + ((long)kc * Bc + row) * 64 + cg);
#pragma unroll
        for (int v4 = 0; v4 < 4; v4++) {
            float4 v = p[v4];
            s[v4 * 4 + 0] += v.x; s[v4 * 4 + 1] += v.y;
            s[v4 * 4 + 2] += v.z; s[v4 * 4 + 3] += v.w;
        }
    }
#pragma unroll
    for (int j = 0; j < 16; j++) {
        const int c = cg + j;
        if (c < NC_) out[row * NC_ + c] = s[j] + cconst[c];
    }
}

// ---------------------------------------------------------------------------
extern "C" void kernel_launch(void* const* d_in, const int* in_sizes, int n_in,
                              void* d_out, int out_size, void* d_ws, size_t ws_size,
                              hipStream_t stream)
{
    const float* x  = (const float*)d_in[0];
    const float* p1 = (const float*)d_in[1];
    const float* p2 = (const float*)d_in[2];
    const float* pf = (const float*)d_in[3];
    const float* W0 = (const float*)d_in[4];
    const float* b0 = (const float*)d_in[5];
    const float* W1 = (const float*)d_in[6];
    const float* b1 = (const float*)d_in[7];
    const float* W2 = (const float*)d_in[8];
    const float* b2 = (const float*)d_in[9];
    float* out = (float*)d_out;

    char* ws = (char*)d_ws;
    size_t off = 0;
    auto alloc = [&](size_t bytes) -> void* {
        void* p = ws + off;
        off += (bytes + 255) & ~(size_t)255;
        return p;
    };
    float* P1n    = (float*)alloc(64 * sizeof(float));
    float* P2n    = (float*)alloc(64 * sizeof(float));
    float* wfin   = (float*)alloc(8 * sizeof(float));
    float* cconst = (float*)alloc(64 * sizeof(float));
    unsigned short* W0r   = (unsigned short*)alloc((size_t)4096 * 512 * 2);
    unsigned short* W1t   = (unsigned short*)alloc((size_t)U_ * 512 * 512 * 2);
    unsigned short* Woutt = (unsigned short*)alloc((size_t)64 * 4096 * 2);
    unsigned short* xb    = (unsigned short*)alloc((size_t)B_ * 512 * 2);

    // L3-RESIDENT chunking: cap Bc at 4096 so a1+h1 (67 MB) live in the
    // 256 MB Infinity Cache across the whole launch (intermediates never
    // stream to HBM). Fall back to smaller if the workspace is tight.
    size_t remain = ws_size > off ? ws_size - off : 0;
    int Bc = 2048;
    for (int cand = 4096; cand >= 2048; cand >>= 1) {
        size_t need = 2ull * 8 * cand * 512 * 2 + 4ull * cand * 64 * 4 + 1024;
        if (need <= remain) { Bc = cand; break; }
    }
    unsigned short* a1 = (unsigned short*)alloc(8ull * Bc * 512 * 2);
    unsigned short* h1 = (unsigned short*)alloc(8ull * Bc * 512 * 2);
    float* partial     = (float*)alloc(4ull * Bc * 64 * 4);

    prep_kernel<<<1, 64, 0, stream>>>(p1, p2, pf, b2, P1n, P2n, wfin, cconst);
    reorder_w0<<<dim3(16, 16, 8), 256, 0, stream>>>(W0, W0r);
    transpose_w<<<dim3(16, 16, 8), 256, 0, stream>>>(W1, W1t);
    wout_build<<<dim3(1024), 256, 0, stream>>>(W2, P2n, wfin, Woutt);
    convert_x<<<dim3(B_ * 512 / 8 / 256), 256, 0, stream>>>(x, xb, (long)B_ * 512);

    const int Mb = Bc / 128;
    const long plane = (long)Bc * 512;
    for (int bb = 0; bb < B_; bb += Bc) {
        gemm0_mix<<<dim3(16 * Mb), 256, 0, stream>>>(
            xb + (long)bb * 512, W0r, b0, P1n, a1, plane);
        gemm_h<<<dim3(32 * Mb), 256, 0, stream>>>(a1, W1t, b1, h1, plane);
        gemm_out<<<dim3(4 * (Bc / 64)), 256, 0, stream>>>(h1, Woutt, partial, plane, Bc);
        reduce_out<<<dim3(Bc / 64), 256, 0, stream>>>(
            partial, cconst, out + (long)bb * NC_, Bc);
    }
}

// Round 9
// 350.364 us; speedup vs baseline: 1.0948x; 1.0948x over previous
//
#include <hip/hip_runtime.h>

#define U_   8
#define B_   16384
#define NC_  62

typedef __attribute__((ext_vector_type(8))) short bfrag;   // 8 bf16 (4 VGPRs)
typedef __attribute__((ext_vector_type(4))) float facc;    // 4 fp32 acc

__device__ __forceinline__ float bf2f(unsigned int lo16) {
    union { unsigned int i; float f; } v;
    v.i = lo16 << 16;
    return v.f;
}
__device__ __forceinline__ unsigned short f2bf(float f) {
    unsigned int x = __float_as_uint(f);
    return (unsigned short)((x + 0x7fffu + ((x >> 16) & 1u)) >> 16);
}
__device__ __forceinline__ void gl2lds16(const void* g, void* l) {
    __builtin_amdgcn_global_load_lds(
        (const __attribute__((address_space(1))) void*)g,
        (__attribute__((address_space(3))) void*)l, 16, 0, 0);
}
// compiler-level fence: pins issue order of memory ops (no HW cost)
__device__ __forceinline__ void cfence() { asm volatile("" ::: "memory"); }
// plain raw barrier (no counter drain) — only where no LDS WAR follows
__device__ __forceinline__ void bar() {
    asm volatile("" ::: "memory");
    __builtin_amdgcn_s_barrier();
    asm volatile("" ::: "memory");
}
// recycle barrier: drain lgkmcnt so this wave's ds_reads are IN REGISTERS
// before anyone overwrites the LDS buffer (rule-#18 hazard). vmcnt NOT drained.
__device__ __forceinline__ void barL() {
    asm volatile("s_waitcnt lgkmcnt(0)" ::: "memory");
    __builtin_amdgcn_s_barrier();
    asm volatile("" ::: "memory");
}
#define VMCNT(n) asm volatile("s_waitcnt vmcnt(" #n ")" ::: "memory")

// ---------------------------------------------------------------------------
// prep: normalized policies, final per-unit weights, folded output bias
// ---------------------------------------------------------------------------
__global__ void prep_kernel(const float* __restrict__ p1, const float* __restrict__ p2,
                            const float* __restrict__ pf, const float* __restrict__ b2,
                            float* __restrict__ P1n, float* __restrict__ P2n,
                            float* __restrict__ wfin, float* __restrict__ cconst)
{
    int t = threadIdx.x;
    if (t >= 64) return;
    int row = t >> 3;
    float s1 = 0.f, s2 = 0.f;
    for (int f = 0; f < 8; f++) { s1 += p1[row * 8 + f]; s2 += p2[row * 8 + f]; }
    P1n[t] = p1[t] * (s1 > 0.f ? 1.f / s1 : 1.f);
    P2n[t] = p2[t] * (s2 > 0.f ? 1.f / s2 : 1.f);
    float d = 0.f;
    for (int j = 0; j < 8; j++) d += pf[j];
    float inv = d > 0.f ? 1.f / d : 1.f;
    float wv[8];
    for (int j = 0; j < 8; j++) {
        float v = pf[j];
        for (int i = j; i < 8; i++) v *= inv;   // inv applied (8-j) times
        wv[j] = v;
    }
    if (t < 8) wfin[t] = wv[t];
    float cc = 0.f;
    if (t < NC_) for (int u = 0; u < 8; u++) cc += wv[u] * b2[u * NC_ + t];
    cconst[t] = cc;
}

// ---------------------------------------------------------------------------
// reorder_w0: W0 [u][k=512][n=512] fp32 -> W0r[n'][k] bf16,
//             n' = (n>>5)*256 + u*32 + (n&31)   (256-col groups: 8u x 32f)
// ---------------------------------------------------------------------------
__global__ __launch_bounds__(256) void reorder_w0(
    const float* __restrict__ W0, unsigned short* __restrict__ W0r)
{
    __shared__ float tile[32][33];
    const int u  = blockIdx.z;
    const int n0 = blockIdx.x * 32, k0 = blockIdx.y * 32;
    const int tx = threadIdx.x & 31, ty = threadIdx.x >> 5;
    const float* Wb = W0 + (long)u * 512 * 512;
#pragma unroll
    for (int i = 0; i < 4; i++)
        tile[ty + i * 8][tx] = Wb[(long)(k0 + ty + i * 8) * 512 + n0 + tx];
    __syncthreads();
#pragma unroll
    for (int i = 0; i < 4; i++) {
        int n = n0 + ty + i * 8, k = k0 + tx;
        int np = (n >> 5) * 256 + u * 32 + (n & 31);
        W0r[(long)np * 512 + k] = f2bf(tile[tx][ty + i * 8]);
    }
}

// ---------------------------------------------------------------------------
// transpose_w: W [u][k=512][n=512] fp32 -> Wt [u][n][k] bf16
// ---------------------------------------------------------------------------
__global__ __launch_bounds__(256) void transpose_w(
    const float* __restrict__ W, unsigned short* __restrict__ Wt)
{
    __shared__ float tile[32][33];
    const int u  = blockIdx.z;
    const int n0 = blockIdx.x * 32, k0 = blockIdx.y * 32;
    const int tx = threadIdx.x & 31, ty = threadIdx.x >> 5;
    const float* Wb = W + (long)u * 512 * 512;
#pragma unroll
    for (int i = 0; i < 4; i++)
        tile[ty + i * 8][tx] = Wb[(long)(k0 + ty + i * 8) * 512 + n0 + tx];
    __syncthreads();
    unsigned short* Wo = Wt + (long)u * 512 * 512;
#pragma unroll
    for (int i = 0; i < 4; i++) {
        int n = n0 + ty + i * 8, k = k0 + tx;
        Wo[(long)n * 512 + k] = f2bf(tile[tx][ty + i * 8]);
    }
}

// ---------------------------------------------------------------------------
// wout_build: Woutt[c][f*512+k] = sum_u wfin[u]*P2n[u,f]*W2[u][k][c]  (c<62)
// ---------------------------------------------------------------------------
__global__ __launch_bounds__(256) void wout_build(
    const float* __restrict__ W2, const float* __restrict__ P2n,
    const float* __restrict__ wfin, unsigned short* __restrict__ Woutt)
{
    const int c   = threadIdx.x & 63;
    const int row = blockIdx.x * 4 + (threadIdx.x >> 6);   // [0,4096)
    const int f = row >> 9, k = row & 511;
    float s = 0.f;
    if (c < NC_) {
#pragma unroll
        for (int u = 0; u < 8; u++)
            s += wfin[u] * P2n[u * 8 + f] * W2[((long)u * 512 + k) * NC_ + c];
    }
    Woutt[(long)c * 4096 + row] = f2bf(s);
}

// ---------------------------------------------------------------------------
// x fp32 -> bf16, 8 elems/thread
// ---------------------------------------------------------------------------
__global__ __launch_bounds__(256) void convert_x(
    const float* __restrict__ x, unsigned short* __restrict__ xb, long n)
{
    long i = ((long)blockIdx.x * 256 + threadIdx.x) * 8;
    if (i >= n) return;
    const float4* xp = (const float4*)(x + i);
    float4 a = xp[0], b = xp[1];
    uint4 o;
    o.x = f2bf(a.x) | ((unsigned)f2bf(a.y) << 16);
    o.y = f2bf(a.z) | ((unsigned)f2bf(a.w) << 16);
    o.z = f2bf(b.x) | ((unsigned)f2bf(b.y) << 16);
    o.w = f2bf(b.z) | ((unsigned)f2bf(b.w) << 16);
    *(uint4*)(xb + i) = o;
}

// ---------------------------------------------------------------------------
// gemm0_mix v6b (measured 55.3 us, clean): 256 thr / 4 waves 2x2,
// 128 rows x 256 cols, BK=32, dbuf + barL + counted vmcnt, planar a1 out.
// LDS = 67584 B -> 2 blocks/CU.
// ---------------------------------------------------------------------------
__global__ __launch_bounds__(256, 2) void gemm0_mix(
    const unsigned short* __restrict__ xb, const unsigned short* __restrict__ W0r,
    const float* __restrict__ b0, const float* __restrict__ P1n,
    unsigned short* __restrict__ a1, long plane)
{
    __shared__ __align__(16) unsigned short sm[33792];   // 67584 B
    const int tid = threadIdx.x, w = tid >> 6, lane = tid & 63;
    const int flat = blockIdx.x;
    const int xcd = flat & 7, seq = flat >> 3;
    const int ng = xcd * 2 + (seq & 1);           // 2 n-groups per XCD
    const long mBase = (long)(seq >> 1) * 128;

    const int lr = lane >> 2;                          // row within 16-row chunk
    const int lg = (lane & 3) ^ ((lane >> 3) & 3);     // swizzled source granule
    const int wm = w >> 1, wn = w & 1;
    const int r = lane & 15, q = lane >> 4;
    const int xq = (q ^ ((r >> 1) & 3)) * 8;           // per-lane read slot offset

    facc acc[4][8];
#pragma unroll
    for (int i = 0; i < 4; i++)
#pragma unroll
        for (int j = 0; j < 8; j++) acc[i][j] = (facc){0.f, 0.f, 0.f, 0.f};

    auto stage = [&](int buf, int kt) {               // 6 gl2lds per wave
        const int k0 = kt * 32;
        unsigned short* dA = sm + buf * 4096;                 // [128][32]
        unsigned short* dB = sm + 8192 + buf * 8192;          // [256][32]
#pragma unroll
        for (int i = 0; i < 2; i++) {
            const int c = w * 2 + i;                          // 8 A-chunks
            gl2lds16(xb + (mBase + c * 16 + lr) * 512 + k0 + lg * 8, dA + c * 512);
        }
#pragma unroll
        for (int i = 0; i < 4; i++) {
            const int c = w * 4 + i;                          // 16 B-chunks
            gl2lds16(W0r + ((long)ng * 256 + c * 16 + lr) * 512 + k0 + lg * 8,
                     dB + c * 512);
        }
    };
    auto compute = [&](int buf) {
        const unsigned short* sA = sm + buf * 4096;
        const unsigned short* sB = sm + 8192 + buf * 8192;
        bfrag aF[4], bF[8];
#pragma unroll
        for (int mt = 0; mt < 4; mt++)
            aF[mt] = *(const bfrag*)&sA[(wm * 64 + mt * 16 + r) * 32 + xq];
#pragma unroll
        for (int nt = 0; nt < 8; nt++)
            bF[nt] = *(const bfrag*)&sB[(wn * 128 + nt * 16 + r) * 32 + xq];
#pragma unroll
        for (int mt = 0; mt < 4; mt++)
#pragma unroll
            for (int nt = 0; nt < 8; nt++)
                acc[mt][nt] = __builtin_amdgcn_mfma_f32_16x16x32_bf16(
                    aF[mt], bF[nt], acc[mt][nt], 0, 0, 0);
    };

    stage(0, 0);
    cfence();            // pin issue groups so vmcnt counting is exact
    stage(1, 1);
    VMCNT(6);            // kt0's 6 loads done (kt1's 6 still in flight)
    bar();
#pragma unroll
    for (int t = 0; t < 16; ++t) {
        compute(t & 1);
        if (t <= 13) {
            barL();                    // ds_reads of buf t&1 in regs, all waves
            stage(t & 1, t + 2);       // refill it for iter t+2
            VMCNT(6);                  // loads for iter t+1 complete
            bar();
        } else if (t == 14) {
            VMCNT(0);                  // drain kt15 loads
            bar();
        } else {
            barL();                    // epilogue overwrites LDS next
        }
    }

    // epilogue: acc -> sm as h0 tile [128 rows][264]
#pragma unroll
    for (int nt = 0; nt < 8; nt++) {
        const int cl = wn * 128 + nt * 16 + r;     // u = cl>>5, f = cl&31
        const float bv = b0[(cl >> 5) * 512 + ng * 32 + (cl & 31)];
#pragma unroll
        for (int mt = 0; mt < 4; mt++) {
            const int rowb = wm * 64 + mt * 16 + q * 4;
#pragma unroll
            for (int rg = 0; rg < 4; rg++) {
                float v = acc[mt][nt][rg] + bv;
                v = v > 0.f ? v : 0.f;
                sm[(rowb + rg) * 264 + cl] = f2bf(v);
            }
        }
    }
    __syncthreads();

    // mix: thread -> (row = tid>>1, fs0 = (tid&1)*16); 32-B planar stores
    float pw[64];
#pragma unroll
    for (int i = 0; i < 64; i++) pw[i] = P1n[i];   // uniform -> SGPRs
    const int row = tid >> 1, fs0 = (tid & 1) * 16;
    float hv[8][16];
#pragma unroll
    for (int u = 0; u < 8; u++) {
        bfrag ha = *(const bfrag*)&sm[row * 264 + u * 32 + fs0];
        bfrag hb = *(const bfrag*)&sm[row * 264 + u * 32 + fs0 + 8];
#pragma unroll
        for (int j = 0; j < 8; j++) {
            hv[u][j]     = bf2f((unsigned int)(unsigned short)ha[j]);
            hv[u][j + 8] = bf2f((unsigned int)(unsigned short)hb[j]);
        }
    }
    const long rowOff = (mBase + row) * 512 + ng * 32 + fs0;
#pragma unroll
    for (int t = 0; t < 8; t++) {
        float o[16];
#pragma unroll
        for (int j = 0; j < 16; j++) {
            float s = 0.f;
#pragma unroll
            for (int u = 0; u < 8; u++) s = fmaf(pw[t * 8 + u], hv[u][j], s);
            o[j] = s;
        }
        uint4 ov0, ov1;
        ov0.x = f2bf(o[0])  | ((unsigned)f2bf(o[1])  << 16);
        ov0.y = f2bf(o[2])  | ((unsigned)f2bf(o[3])  << 16);
        ov0.z = f2bf(o[4])  | ((unsigned)f2bf(o[5])  << 16);
        ov0.w = f2bf(o[6])  | ((unsigned)f2bf(o[7])  << 16);
        ov1.x = f2bf(o[8])  | ((unsigned)f2bf(o[9])  << 16);
        ov1.y = f2bf(o[10]) | ((unsigned)f2bf(o[11]) << 16);
        ov1.z = f2bf(o[12]) | ((unsigned)f2bf(o[13]) << 16);
        ov1.w = f2bf(o[14]) | ((unsigned)f2bf(o[15]) << 16);
        *(uint4*)(a1 + (long)t * plane + rowOff)     = ov0;
        *(uint4*)(a1 + (long)t * plane + rowOff + 8) = ov1;
    }
}

// ---------------------------------------------------------------------------
// gemm_h v9: FULL-N tile — 64 rows x 512 cols per block, so a1 is read
// EXACTLY ONCE (was 4x at 128x128: ~536 MB -> 134 MB of a1 traffic).
// 256 thr / 4 waves, each wave 64x128 (acc[4][8]); BK=32; dbuf + barL +
// counted vmcnt (9 loads/wave -> VMCNT(9)). W1t[u] (0.5 MB) L2-hot, xcd=u.
// LDS: A 2x4KB + B 2x32KB = 73728 B -> 2 blocks/CU. Epilogue via LDS
// [64][520], full 1-KB contiguous row stores.
// ---------------------------------------------------------------------------
__global__ __launch_bounds__(256, 2) void gemm_h(
    const unsigned short* __restrict__ a1,     // planar [u][rows][512]
    const unsigned short* __restrict__ W1t,    // [u][n][k]
    const float* __restrict__ b1,
    unsigned short* __restrict__ h1, long plane)
{
    __shared__ __align__(16) unsigned short sm[36864];   // 73728 B
    const int tid = threadIdx.x, w = tid >> 6, lane = tid & 63;
    const int flat = blockIdx.x;
    const int u = flat & 7, seq = flat >> 3;             // xcd = u
    const long mBase = (long)seq * 64;

    const int lr = lane >> 2;                          // row within 16-row chunk
    const int lg = (lane & 3) ^ ((lane >> 3) & 3);     // swizzled source granule
    const int r = lane & 15, q = lane >> 4;
    const int xq = (q ^ ((r >> 1) & 3)) * 8;

    const unsigned short* Ab = a1 + (long)u * plane;
    const unsigned short* Bb = W1t + (long)u * 512 * 512;

    facc acc[4][8];
#pragma unroll
    for (int i = 0; i < 4; i++)
#pragma unroll
        for (int j = 0; j < 8; j++) acc[i][j] = (facc){0.f, 0.f, 0.f, 0.f};

    auto stage = [&](int buf, int kt) {               // 9 gl2lds per wave
        const int k0 = kt * 32;
        unsigned short* dA = sm + buf * 2048;                 // [64][32]
        unsigned short* dB = sm + 4096 + buf * 16384;         // [512][32]
        // A: 4 chunks (16 rows x 32 cols each); wave w -> chunk w
        gl2lds16(Ab + (mBase + w * 16 + lr) * 512 + k0 + lg * 8, dA + w * 512);
        // B: 32 chunks; wave w -> chunks 8w..8w+7
#pragma unroll
        for (int i = 0; i < 8; i++) {
            const int c = w * 8 + i;
            gl2lds16(Bb + (long)(c * 16 + lr) * 512 + k0 + lg * 8, dB + c * 512);
        }
    };
    auto compute = [&](int buf) {
        const unsigned short* sA = sm + buf * 2048;
        const unsigned short* sB = sm + 4096 + buf * 16384;
        bfrag aF[4], bF[8];
#pragma unroll
        for (int mt = 0; mt < 4; mt++)
            aF[mt] = *(const bfrag*)&sA[(mt * 16 + r) * 32 + xq];
#pragma unroll
        for (int nt = 0; nt < 8; nt++)
            bF[nt] = *(const bfrag*)&sB[(w * 128 + nt * 16 + r) * 32 + xq];
#pragma unroll
        for (int mt = 0; mt < 4; mt++)
#pragma unroll
            for (int nt = 0; nt < 8; nt++)
                acc[mt][nt] = __builtin_amdgcn_mfma_f32_16x16x32_bf16(
                    aF[mt], bF[nt], acc[mt][nt], 0, 0, 0);
    };

    stage(0, 0);
    cfence();            // pin issue groups so vmcnt counting is exact
    stage(1, 1);
    VMCNT(9);            // kt0's 9 loads done (kt1's 9 still in flight)
    bar();
#pragma unroll
    for (int t = 0; t < 16; ++t) {
        compute(t & 1);
        if (t <= 13) {
            barL();                    // ds_reads of buf t&1 in regs, all waves
            stage(t & 1, t + 2);       // refill it for iter t+2
            VMCNT(9);                  // loads for iter t+1 complete
            bar();
        } else if (t == 14) {
            VMCNT(0);                  // drain kt15 loads
            bar();
        } else {
            barL();                    // epilogue overwrites LDS next
        }
    }

    // epilogue: acc -> sm as C tile [64][520]  (66560 B <= 73728 B)
#pragma unroll
    for (int nt = 0; nt < 8; nt++) {
        const int col = w * 128 + nt * 16 + r;
        const float bv = b1[u * 512 + col];
#pragma unroll
        for (int mt = 0; mt < 4; mt++) {
            const int rowb = mt * 16 + q * 4;
#pragma unroll
            for (int rg = 0; rg < 4; rg++) {
                float v = acc[mt][nt][rg] + bv;
                v = v > 0.f ? v : 0.f;
                sm[(rowb + rg) * 520 + col] = f2bf(v);
            }
        }
    }
    __syncthreads();

    // coalesced write: full 1-KB contiguous rows (64 rows x 512 cols)
    unsigned short* Cb = h1 + (long)u * plane + mBase * 512;
#pragma unroll
    for (int it = 0; it < 16; it++) {
        const int g = tid + it * 256;
        const int row = g >> 6, gr = g & 63;
        *(uint4*)(Cb + (long)row * 512 + gr * 8) = *(const uint4*)&sm[row * 520 + gr * 8];
    }
}

// ---------------------------------------------------------------------------
// gemm_out v6b (proven): split-K=2 (kc over 4 h1-planes each), 64x64 tile,
// BK=64, dbuf + counted vmcnt + barL recycle over 32 k-iters, xor-swizzle,
// fp32 partial with 64-B-run stores.  LDS = 32 KB.
// ---------------------------------------------------------------------------
__global__ __launch_bounds__(256, 1) void gemm_out(
    const unsigned short* __restrict__ h1,     // planar [f][rows][512]
    const unsigned short* __restrict__ Bt,     // Woutt [64 c][4096]
    float* __restrict__ partial, long plane, int Bc)
{
    __shared__ __align__(16) unsigned short sm[16384];   // 32768 B
    const int tid = threadIdx.x, w = tid >> 6, lane = tid & 63;
    const int flat = blockIdx.x;
    const int kc = flat & 1;
    const long mBase = (long)(flat >> 1) * 64;

    const int lr = lane >> 3, lg = (lane & 7) ^ lr;
    const int wm = w >> 1, wn = w & 1;
    const int r = lane & 15, q = lane >> 4;
    const int x7 = r & 7;

    facc acc[2][2];
#pragma unroll
    for (int i = 0; i < 2; i++)
#pragma unroll
        for (int j = 0; j < 2; j++) acc[i][j] = (facc){0.f, 0.f, 0.f, 0.f};

    auto stage = [&](int buf, int it) {               // 4 gl2lds per wave
        const int u = kc * 4 + (it >> 3);
        const int kk = (it & 7) * 64;
        unsigned short* dA = sm + buf * 4096;
        unsigned short* dB = sm + 8192 + buf * 4096;
#pragma unroll
        for (int i = 0; i < 2; i++) {
            const int c = w * 2 + i;
            gl2lds16(h1 + (long)u * plane + (mBase + c * 8 + lr) * 512 + kk + lg * 8,
                     dA + c * 512);
            gl2lds16(Bt + (long)(c * 8 + lr) * 4096 + u * 512 + kk + lg * 8,
                     dB + c * 512);
        }
    };
    auto compute = [&](int buf) {
        const unsigned short* sA = sm + buf * 4096;
        const unsigned short* sB = sm + 8192 + buf * 4096;
#pragma unroll
        for (int h = 0; h < 2; h++) {
            const int xg = ((h * 4 + q) ^ x7) * 8;
            bfrag aF[2], bF[2];
#pragma unroll
            for (int mt = 0; mt < 2; mt++)
                aF[mt] = *(const bfrag*)&sA[(wm * 32 + mt * 16 + r) * 64 + xg];
#pragma unroll
            for (int nt = 0; nt < 2; nt++)
                bF[nt] = *(const bfrag*)&sB[(wn * 32 + nt * 16 + r) * 64 + xg];
#pragma unroll
            for (int mt = 0; mt < 2; mt++)
#pragma unroll
                for (int nt = 0; nt < 2; nt++)
                    acc[mt][nt] = __builtin_amdgcn_mfma_f32_16x16x32_bf16(
                        aF[mt], bF[nt], acc[mt][nt], 0, 0, 0);
        }
    };

    stage(0, 0);
    cfence();            // pin issue groups
    stage(1, 1);
    VMCNT(4);
    bar();
#pragma unroll
    for (int t = 0; t < 32; ++t) {
        compute(t & 1);
        if (t <= 29) {
            barL();
            stage(t & 1, t + 2);
            VMCNT(4);
            bar();
        } else if (t == 30) {
            VMCNT(0);
            bar();
        }
        // t == 31: no LDS reuse afterwards, registers go straight to global
    }

    float* pb = partial + ((long)kc * Bc + mBase) * 64;
#pragma unroll
    for (int nt = 0; nt < 2; nt++) {
        const int col = wn * 32 + nt * 16 + r;
#pragma unroll
        for (int mt = 0; mt < 2; mt++) {
#pragma unroll
            for (int rg = 0; rg < 4; rg++) {
                const int row = wm * 32 + mt * 16 + q * 4 + rg;
                pb[(long)row * 64 + col] = acc[mt][nt][rg];
            }
        }
    }
}

// ---------------------------------------------------------------------------
// reduce_out: out[row][c] = partial[0]+partial[1] + cconst[c]
// ---------------------------------------------------------------------------
__global__ __launch_bounds__(256) void reduce_out(
    const float* __restrict__ partial, const float* __restrict__ cconst,
    float* __restrict__ out, int Bc)
{
    const long flat = (long)blockIdx.x * 256 + threadIdx.x;
    const long row = flat >> 2;
    const int cg = (int)(flat & 3) * 16;
    float s[16];
#pragma unroll
    for (int j = 0; j < 16; j++) s[j] = 0.f;
#pragma unroll
    for (int kc = 0; kc < 2; kc++) {
        const float4* p = (const float4*)(partial + ((long)kc * Bc + row) * 64 + cg);
#pragma unroll
        for (int v4 = 0; v4 < 4; v4++) {
            float4 v = p[v4];
            s[v4 * 4 + 0] += v.x; s[v4 * 4 + 1] += v.y;
            s[v4 * 4 + 2] += v.z; s[v4 * 4 + 3] += v.w;
        }
    }
#pragma unroll
    for (int j = 0; j < 16; j++) {
        const int c = cg + j;
        if (c < NC_) out[row * NC_ + c] = s[j] + cconst[c];
    }
}

// ---------------------------------------------------------------------------
extern "C" void kernel_launch(void* const* d_in, const int* in_sizes, int n_in,
                              void* d_out, int out_size, void* d_ws, size_t ws_size,
                              hipStream_t stream)
{
    const float* x  = (const float*)d_in[0];
    const float* p1 = (const float*)d_in[1];
    const float* p2 = (const float*)d_in[2];
    const float* pf = (const float*)d_in[3];
    const float* W0 = (const float*)d_in[4];
    const float* b0 = (const float*)d_in[5];
    const float* W1 = (const float*)d_in[6];
    const float* b1 = (const float*)d_in[7];
    const float* W2 = (const float*)d_in[8];
    const float* b2 = (const float*)d_in[9];
    float* out = (float*)d_out;

    char* ws = (char*)d_ws;
    size_t off = 0;
    auto alloc = [&](size_t bytes) -> void* {
        void* p = ws + off;
        off += (bytes + 255) & ~(size_t)255;
        return p;
    };
    float* P1n    = (float*)alloc(64 * sizeof(float));
    float* P2n    = (float*)alloc(64 * sizeof(float));
    float* wfin   = (float*)alloc(8 * sizeof(float));
    float* cconst = (float*)alloc(64 * sizeof(float));
    unsigned short* W0r   = (unsigned short*)alloc((size_t)4096 * 512 * 2);
    unsigned short* W1t   = (unsigned short*)alloc((size_t)U_ * 512 * 512 * 2);
    unsigned short* Woutt = (unsigned short*)alloc((size_t)64 * 4096 * 2);
    unsigned short* xb    = (unsigned short*)alloc((size_t)B_ * 512 * 2);

    // a1 + h1 planar (8 planes x Bc x 512 bf16 each) + fp32 partial (2 x Bc x 64)
    size_t remain = ws_size > off ? ws_size - off : 0;
    int Bc = 2048;
    for (int cand = B_; cand >= 2048; cand >>= 1) {
        size_t need = 2ull * 8 * cand * 512 * 2 + 2ull * cand * 64 * 4 + 1024;
        if (need <= remain) { Bc = cand; break; }
    }
    unsigned short* a1 = (unsigned short*)alloc(8ull * Bc * 512 * 2);
    unsigned short* h1 = (unsigned short*)alloc(8ull * Bc * 512 * 2);
    float* partial     = (float*)alloc(2ull * Bc * 64 * 4);

    prep_kernel<<<1, 64, 0, stream>>>(p1, p2, pf, b2, P1n, P2n, wfin, cconst);
    reorder_w0<<<dim3(16, 16, 8), 256, 0, stream>>>(W0, W0r);
    transpose_w<<<dim3(16, 16, 8), 256, 0, stream>>>(W1, W1t);
    wout_build<<<dim3(1024), 256, 0, stream>>>(W2, P2n, wfin, Woutt);
    convert_x<<<dim3(B_ * 512 / 8 / 256), 256, 0, stream>>>(x, xb, (long)B_ * 512);

    const int Mb = Bc / 128;
    const long plane = (long)Bc * 512;
    for (int bb = 0; bb < B_; bb += Bc) {
        gemm0_mix<<<dim3(16 * Mb), 256, 0, stream>>>(
            xb + (long)bb * 512, W0r, b0, P1n, a1, plane);
        gemm_h<<<dim3(8 * (Bc / 64)), 256, 0, stream>>>(a1, W1t, b1, h1, plane);
        gemm_out<<<dim3(2 * (Bc / 64)), 256, 0, stream>>>(h1, Woutt, partial, plane, Bc);
        reduce_out<<<dim3(Bc / 64), 256, 0, stream>>>(
            partial, cconst, out + (long)bb * NC_, Bc);
    }
}

// Round 10
// 307.501 us; speedup vs baseline: 1.2474x; 1.1394x over previous
//
#include <hip/hip_runtime.h>

#define U_   8
#define B_   16384
#define NC_  62

typedef __attribute__((ext_vector_type(8))) short bfrag;   // 8 bf16 (4 VGPRs)
typedef __attribute__((ext_vector_type(4))) float facc;    // 4 fp32 acc

__device__ __forceinline__ float bf2f(unsigned int lo16) {
    union { unsigned int i; float f; } v;
    v.i = lo16 << 16;
    return v.f;
}
__device__ __forceinline__ unsigned short f2bf(float f) {
    unsigned int x = __float_as_uint(f);
    return (unsigned short)((x + 0x7fffu + ((x >> 16) & 1u)) >> 16);
}
__device__ __forceinline__ void gl2lds16(const void* g, void* l) {
    __builtin_amdgcn_global_load_lds(
        (const __attribute__((address_space(1))) void*)g,
        (__attribute__((address_space(3))) void*)l, 16, 0, 0);
}
// compiler-level fence: pins issue order of memory ops (no HW cost)
__device__ __forceinline__ void cfence() { asm volatile("" ::: "memory"); }
// plain raw barrier (no counter drain) — only where no LDS WAR follows
__device__ __forceinline__ void bar() {
    asm volatile("" ::: "memory");
    __builtin_amdgcn_s_barrier();
    asm volatile("" ::: "memory");
}
// recycle barrier: drain lgkmcnt so this wave's ds_reads are IN REGISTERS
// before anyone overwrites the LDS buffer (rule-#18 hazard). vmcnt NOT drained.
__device__ __forceinline__ void barL() {
    asm volatile("s_waitcnt lgkmcnt(0)" ::: "memory");
    __builtin_amdgcn_s_barrier();
    asm volatile("" ::: "memory");
}
#define VMCNT(n) asm volatile("s_waitcnt vmcnt(" #n ")" ::: "memory")
#define LGKM0()  asm volatile("s_waitcnt lgkmcnt(0)" ::: "memory")

// ---------------------------------------------------------------------------
// prep_all: one kernel, block-range dispatch.
//   [0,2048)    reorder_w0:  W0 fp32 -> W0r[n'][k] bf16
//   [2048,4096) transpose_w: W1 fp32 -> W1t[u][n][k] bf16
//   [4096,5120) wout_build (P2n/wfin inlined)
//   [5120,9216) convert_x
// ---------------------------------------------------------------------------
__global__ __launch_bounds__(256) void prep_all(
    const float* __restrict__ p2, const float* __restrict__ pf,
    const float* __restrict__ W0, const float* __restrict__ W1,
    const float* __restrict__ W2, const float* __restrict__ x,
    unsigned short* __restrict__ W0r, unsigned short* __restrict__ W1t,
    unsigned short* __restrict__ Woutt, unsigned short* __restrict__ xb)
{
    __shared__ float tile[32][33];
    const int b = blockIdx.x;

    if (b < 4096) {                       // the two weight transposes
        const bool isW0 = (b < 2048);
        const int bb = isW0 ? b : b - 2048;
        const int u  = bb >> 8;
        const int n0 = (bb & 15) * 32, k0 = ((bb >> 4) & 15) * 32;
        const int tx = threadIdx.x & 31, ty = threadIdx.x >> 5;
        const float* Wb = (isW0 ? W0 : W1) + (long)u * 512 * 512;
#pragma unroll
        for (int i = 0; i < 4; i++)
            tile[ty + i * 8][tx] = Wb[(long)(k0 + ty + i * 8) * 512 + n0 + tx];
        __syncthreads();
        if (isW0) {
#pragma unroll
            for (int i = 0; i < 4; i++) {
                int n = n0 + ty + i * 8, k = k0 + tx;
                int np = (n >> 5) * 256 + u * 32 + (n & 31);
                W0r[(long)np * 512 + k] = f2bf(tile[tx][ty + i * 8]);
            }
        } else {
            unsigned short* Wo = W1t + (long)u * 512 * 512;
#pragma unroll
            for (int i = 0; i < 4; i++) {
                int n = n0 + ty + i * 8, k = k0 + tx;
                Wo[(long)n * 512 + k] = f2bf(tile[tx][ty + i * 8]);
            }
        }
    } else if (b < 5120) {                // wout_build, P2n/wfin inline
        const int bx = b - 4096;
        const int c   = threadIdx.x & 63;
        const int row = bx * 4 + (threadIdx.x >> 6);   // [0,4096)
        const int f = row >> 9, k = row & 511;
        float d = 0.f;
#pragma unroll
        for (int j = 0; j < 8; j++) d += pf[j];
        float inv = d > 0.f ? 1.f / d : 1.f;
        float s = 0.f;
        if (c < NC_) {
#pragma unroll
            for (int u = 0; u < 8; u++) {
                float wv = pf[u];
#pragma unroll
                for (int i = u; i < 8; i++) wv *= inv;     // inv applied (8-u) times
                float s2 = 0.f;
#pragma unroll
                for (int ff = 0; ff < 8; ff++) s2 += p2[u * 8 + ff];
                float p2n = p2[u * 8 + f] * (s2 > 0.f ? 1.f / s2 : 1.f);
                s += wv * p2n * W2[((long)u * 512 + k) * NC_ + c];
            }
        }
        Woutt[(long)c * 4096 + row] = f2bf(s);
    } else {                              // convert_x
        const int bx = b - 5120;
        long i = ((long)bx * 256 + threadIdx.x) * 8;
        if (i >= (long)B_ * 512) return;
        const float4* xp = (const float4*)(x + i);
        float4 a = xp[0], bb4 = xp[1];
        uint4 o;
        o.x = f2bf(a.x) | ((unsigned)f2bf(a.y) << 16);
        o.y = f2bf(a.z) | ((unsigned)f2bf(a.w) << 16);
        o.z = f2bf(bb4.x) | ((unsigned)f2bf(bb4.y) << 16);
        o.w = f2bf(bb4.z) | ((unsigned)f2bf(bb4.w) << 16);
        *(uint4*)(xb + i) = o;
    }
}

// ---------------------------------------------------------------------------
// gemm0_mix v10 (= v6b, P1n inlined): 256 thr / 4 waves 2x2, 128x256, BK=32,
// dbuf + barL + counted vmcnt, planar a1 out. LDS 67584 B -> 2 blocks/CU.
// ---------------------------------------------------------------------------
__global__ __launch_bounds__(256, 2) void gemm0_mix(
    const unsigned short* __restrict__ xb, const unsigned short* __restrict__ W0r,
    const float* __restrict__ b0, const float* __restrict__ p1,
    unsigned short* __restrict__ a1, long plane)
{
    __shared__ __align__(16) unsigned short sm[33792];   // 67584 B
    const int tid = threadIdx.x, w = tid >> 6, lane = tid & 63;
    const int flat = blockIdx.x;
    const int xcd = flat & 7, seq = flat >> 3;
    const int ng = xcd * 2 + (seq & 1);           // 2 n-groups per XCD
    const long mBase = (long)(seq >> 1) * 128;

    const int lr = lane >> 2;                          // row within 16-row chunk
    const int lg = (lane & 3) ^ ((lane >> 3) & 3);     // swizzled source granule
    const int wm = w >> 1, wn = w & 1;
    const int r = lane & 15, q = lane >> 4;
    const int xq = (q ^ ((r >> 1) & 3)) * 8;           // per-lane read slot offset

    facc acc[4][8];
#pragma unroll
    for (int i = 0; i < 4; i++)
#pragma unroll
        for (int j = 0; j < 8; j++) acc[i][j] = (facc){0.f, 0.f, 0.f, 0.f};

    auto stage = [&](int buf, int kt) {               // 6 gl2lds per wave
        const int k0 = kt * 32;
        unsigned short* dA = sm + buf * 4096;                 // [128][32]
        unsigned short* dB = sm + 8192 + buf * 8192;          // [256][32]
#pragma unroll
        for (int i = 0; i < 2; i++) {
            const int c = w * 2 + i;                          // 8 A-chunks
            gl2lds16(xb + (mBase + c * 16 + lr) * 512 + k0 + lg * 8, dA + c * 512);
        }
#pragma unroll
        for (int i = 0; i < 4; i++) {
            const int c = w * 4 + i;                          // 16 B-chunks
            gl2lds16(W0r + ((long)ng * 256 + c * 16 + lr) * 512 + k0 + lg * 8,
                     dB + c * 512);
        }
    };
    auto compute = [&](int buf) {
        const unsigned short* sA = sm + buf * 4096;
        const unsigned short* sB = sm + 8192 + buf * 8192;
        bfrag aF[4], bF[8];
#pragma unroll
        for (int mt = 0; mt < 4; mt++)
            aF[mt] = *(const bfrag*)&sA[(wm * 64 + mt * 16 + r) * 32 + xq];
#pragma unroll
        for (int nt = 0; nt < 8; nt++)
            bF[nt] = *(const bfrag*)&sB[(wn * 128 + nt * 16 + r) * 32 + xq];
#pragma unroll
        for (int mt = 0; mt < 4; mt++)
#pragma unroll
            for (int nt = 0; nt < 8; nt++)
                acc[mt][nt] = __builtin_amdgcn_mfma_f32_16x16x32_bf16(
                    aF[mt], bF[nt], acc[mt][nt], 0, 0, 0);
    };

    stage(0, 0);
    cfence();            // pin issue groups so vmcnt counting is exact
    stage(1, 1);
    VMCNT(6);            // kt0's 6 loads done (kt1's 6 still in flight)
    bar();
#pragma unroll
    for (int t = 0; t < 16; ++t) {
        compute(t & 1);
        if (t <= 13) {
            barL();                    // ds_reads of buf t&1 in regs, all waves
            stage(t & 1, t + 2);       // refill it for iter t+2
            VMCNT(6);                  // loads for iter t+1 complete
            bar();
        } else if (t == 14) {
            VMCNT(0);                  // drain kt15 loads
            bar();
        } else {
            barL();                    // epilogue overwrites LDS next
        }
    }

    // epilogue: acc -> sm as h0 tile [128 rows][264]
#pragma unroll
    for (int nt = 0; nt < 8; nt++) {
        const int cl = wn * 128 + nt * 16 + r;     // u = cl>>5, f = cl&31
        const float bv = b0[(cl >> 5) * 512 + ng * 32 + (cl & 31)];
#pragma unroll
        for (int mt = 0; mt < 4; mt++) {
            const int rowb = wm * 64 + mt * 16 + q * 4;
#pragma unroll
            for (int rg = 0; rg < 4; rg++) {
                float v = acc[mt][nt][rg] + bv;
                v = v > 0.f ? v : 0.f;
                sm[(rowb + rg) * 264 + cl] = f2bf(v);
            }
        }
    }
    __syncthreads();

    // mix: inline P1n (normalize p1 rows); thread -> (row=tid>>1, fs0=(tid&1)*16)
    float pw[64];
#pragma unroll
    for (int t8 = 0; t8 < 8; t8++) {
        float s1 = 0.f;
#pragma unroll
        for (int f = 0; f < 8; f++) s1 += p1[t8 * 8 + f];
        float inv = s1 > 0.f ? 1.f / s1 : 1.f;
#pragma unroll
        for (int f = 0; f < 8; f++) pw[t8 * 8 + f] = p1[t8 * 8 + f] * inv;
    }
    const int row = tid >> 1, fs0 = (tid & 1) * 16;
    float hv[8][16];
#pragma unroll
    for (int u = 0; u < 8; u++) {
        bfrag ha = *(const bfrag*)&sm[row * 264 + u * 32 + fs0];
        bfrag hb = *(const bfrag*)&sm[row * 264 + u * 32 + fs0 + 8];
#pragma unroll
        for (int j = 0; j < 8; j++) {
            hv[u][j]     = bf2f((unsigned int)(unsigned short)ha[j]);
            hv[u][j + 8] = bf2f((unsigned int)(unsigned short)hb[j]);
        }
    }
    const long rowOff = (mBase + row) * 512 + ng * 32 + fs0;
#pragma unroll
    for (int t = 0; t < 8; t++) {
        float o[16];
#pragma unroll
        for (int j = 0; j < 16; j++) {
            float s = 0.f;
#pragma unroll
            for (int u = 0; u < 8; u++) s = fmaf(pw[t * 8 + u], hv[u][j], s);
            o[j] = s;
        }
        uint4 ov0, ov1;
        ov0.x = f2bf(o[0])  | ((unsigned)f2bf(o[1])  << 16);
        ov0.y = f2bf(o[2])  | ((unsigned)f2bf(o[3])  << 16);
        ov0.z = f2bf(o[4])  | ((unsigned)f2bf(o[5])  << 16);
        ov0.w = f2bf(o[6])  | ((unsigned)f2bf(o[7])  << 16);
        ov1.x = f2bf(o[8])  | ((unsigned)f2bf(o[9])  << 16);
        ov1.y = f2bf(o[10]) | ((unsigned)f2bf(o[11]) << 16);
        ov1.z = f2bf(o[12]) | ((unsigned)f2bf(o[13]) << 16);
        ov1.w = f2bf(o[14]) | ((unsigned)f2bf(o[15]) << 16);
        *(uint4*)(a1 + (long)t * plane + rowOff)     = ov0;
        *(uint4*)(a1 + (long)t * plane + rowOff + 8) = ov1;
    }
}

// ---------------------------------------------------------------------------
// gemm_hout v10: v9 gemm_h (64 rows x 512 cols, full-N, a1 read once) FUSED
// with gemm_out. GEMM-1 -> relu(h1_u) bf16 LDS tile [64][522]; GEMM-2:
// partial[u] = h1_u(64x512) @ Woutt_u(512x64c). Woutt chunks are staged
// PER-WAVE (each wave stages+reads only its own 16-c rows) -> GEMM-2 needs
// no barriers, only per-wave vmcnt/lgkm. h1 never goes to global.
// LDS 75008 B -> 2 blocks/CU.
// ---------------------------------------------------------------------------
__global__ __launch_bounds__(256, 2) void gemm_hout(
    const unsigned short* __restrict__ a1,     // planar [u][rows][512]
    const unsigned short* __restrict__ W1t,    // [u][n][k]
    const float* __restrict__ b1,
    const unsigned short* __restrict__ Woutt,  // [64 c][4096] (k' = u*512+k)
    float* __restrict__ partial, long plane)
{
    __shared__ __align__(16) unsigned short sm[37504];   // 75008 B
    const int tid = threadIdx.x, w = tid >> 6, lane = tid & 63;
    const int flat = blockIdx.x;
    const int u = flat & 7, seq = flat >> 3;             // xcd = u
    const long mBase = (long)seq * 64;
    const long Bc = plane >> 9;

    const int lr = lane >> 2;                          // row within 16-row chunk
    const int lg = (lane & 3) ^ ((lane >> 3) & 3);     // swizzled source granule
    const int r = lane & 15, q = lane >> 4;
    const int xq = (q ^ ((r >> 1) & 3)) * 8;

    const unsigned short* Ab = a1 + (long)u * plane;
    const unsigned short* Bb = W1t + (long)u * 512 * 512;

    facc acc[4][8];
#pragma unroll
    for (int i = 0; i < 4; i++)
#pragma unroll
        for (int j = 0; j < 8; j++) acc[i][j] = (facc){0.f, 0.f, 0.f, 0.f};

    auto stage = [&](int buf, int kt) {               // 9 gl2lds per wave
        const int k0 = kt * 32;
        unsigned short* dA = sm + buf * 2048;                 // [64][32]
        unsigned short* dB = sm + 4096 + buf * 16384;         // [512][32]
        gl2lds16(Ab + (mBase + w * 16 + lr) * 512 + k0 + lg * 8, dA + w * 512);
#pragma unroll
        for (int i = 0; i < 8; i++) {
            const int c = w * 8 + i;
            gl2lds16(Bb + (long)(c * 16 + lr) * 512 + k0 + lg * 8, dB + c * 512);
        }
    };
    auto compute = [&](int buf) {
        const unsigned short* sA = sm + buf * 2048;
        const unsigned short* sB = sm + 4096 + buf * 16384;
        bfrag aF[4], bF[8];
#pragma unroll
        for (int mt = 0; mt < 4; mt++)
            aF[mt] = *(const bfrag*)&sA[(mt * 16 + r) * 32 + xq];
#pragma unroll
        for (int nt = 0; nt < 8; nt++)
            bF[nt] = *(const bfrag*)&sB[(w * 128 + nt * 16 + r) * 32 + xq];
#pragma unroll
        for (int mt = 0; mt < 4; mt++)
#pragma unroll
            for (int nt = 0; nt < 8; nt++)
                acc[mt][nt] = __builtin_amdgcn_mfma_f32_16x16x32_bf16(
                    aF[mt], bF[nt], acc[mt][nt], 0, 0, 0);
    };

    stage(0, 0);
    cfence();
    stage(1, 1);
    VMCNT(9);
    bar();
#pragma unroll
    for (int t = 0; t < 16; ++t) {
        compute(t & 1);
        if (t <= 13) {
            barL();
            stage(t & 1, t + 2);
            VMCNT(9);
            bar();
        } else if (t == 14) {
            VMCNT(0);
            bar();
        } else {
            barL();                    // C-tile write overwrites staging LDS
        }
    }

    // GEMM-1 epilogue: relu(acc+bias) -> bf16 C tile [64][522] at sm base
#pragma unroll
    for (int nt = 0; nt < 8; nt++) {
        const int col = w * 128 + nt * 16 + r;
        const float bv = b1[u * 512 + col];
#pragma unroll
        for (int mt = 0; mt < 4; mt++) {
            const int rowb = mt * 16 + q * 4;
#pragma unroll
            for (int rg = 0; rg < 4; rg++) {
                float v = acc[mt][nt][rg] + bv;
                v = v > 0.f ? v : 0.f;
                sm[(rowb + rg) * 522 + col] = f2bf(v);
            }
        }
    }
    __syncthreads();

    // ---- GEMM-2: out_u(64x64c) = h1_u(64x512) @ Woutt_u^T, K=512 ----
    // Woutt dbuf at shorts [33408, 37504): 2 bufs x [64 c][32 k].
    // Wave w stages & reads ONLY rows w*16..w*16+15 -> no barriers needed.
    unsigned short* Wb0 = sm + 33408;
    const unsigned short* Wg = Woutt + (long)u * 512;   // row stride 4096

    facc acc2[4];
#pragma unroll
    for (int i = 0; i < 4; i++) acc2[i] = (facc){0.f, 0.f, 0.f, 0.f};

    auto stage2 = [&](int buf, int kt) {              // 1 gl2lds per wave
        gl2lds16(Wg + (long)(w * 16 + lr) * 4096 + kt * 32 + lg * 8,
                 Wb0 + buf * 2048 + w * 512);
    };
    auto compute2 = [&](int buf, int kt) {
        const unsigned short* sW = Wb0 + buf * 2048;
        bfrag bW = *(const bfrag*)&sW[(w * 16 + r) * 32 + xq];
#pragma unroll
        for (int mt = 0; mt < 4; mt++) {
            // A from unswizzled C tile: lane r = h1 row, q = k-granule (plain)
            bfrag aH = *(const bfrag*)&sm[(mt * 16 + r) * 522 + kt * 32 + q * 8];
            acc2[mt] = __builtin_amdgcn_mfma_f32_16x16x32_bf16(
                aH, bW, acc2[mt], 0, 0, 0);
        }
    };

    stage2(0, 0);
    cfence();
    stage2(1, 1);
#pragma unroll
    for (int t = 0; t < 16; ++t) {
        if (t < 15) { VMCNT(1); } else { VMCNT(0); }   // own loads only
        compute2(t & 1, t);
        if (t <= 13) {
            LGKM0();                   // own ds_reads of buf t&1 in regs
            stage2(t & 1, t + 2);
        }
    }

    // partial[u][row][c] fp32
    float* pb = partial + ((long)u * Bc + mBase) * 64;
#pragma unroll
    for (int mt = 0; mt < 4; mt++) {
#pragma unroll
        for (int rg = 0; rg < 4; rg++) {
            const int prow = mt * 16 + q * 4 + rg;
            pb[(long)prow * 64 + w * 16 + r] = acc2[mt][rg];
        }
    }
}

// ---------------------------------------------------------------------------
// reduce_out: out[row][c] = sum_u partial[u] + cconst[c] (cconst inlined)
// ---------------------------------------------------------------------------
__global__ __launch_bounds__(256) void reduce_out(
    const float* __restrict__ partial, const float* __restrict__ pf,
    const float* __restrict__ b2, float* __restrict__ out, int Bc)
{
    const long flat = (long)blockIdx.x * 256 + threadIdx.x;
    const long row = flat >> 2;
    const int cg = (int)(flat & 3) * 16;
    float s[16];
#pragma unroll
    for (int j = 0; j < 16; j++) s[j] = 0.f;
#pragma unroll
    for (int u = 0; u < 8; u++) {
        const float4* p = (const float4*)(partial + ((long)u * Bc + row) * 64 + cg);
#pragma unroll
        for (int v4 = 0; v4 < 4; v4++) {
            float4 v = p[v4];
            s[v4 * 4 + 0] += v.x; s[v4 * 4 + 1] += v.y;
            s[v4 * 4 + 2] += v.z; s[v4 * 4 + 3] += v.w;
        }
    }
    // cconst inline
    float d = 0.f;
#pragma unroll
    for (int j = 0; j < 8; j++) d += pf[j];
    float inv = d > 0.f ? 1.f / d : 1.f;
    float wv[8];
#pragma unroll
    for (int j = 0; j < 8; j++) {
        float v = pf[j];
#pragma unroll
        for (int i = j; i < 8; i++) v *= inv;
        wv[j] = v;
    }
#pragma unroll
    for (int j = 0; j < 16; j++) {
        const int c = cg + j;
        if (c < NC_) {
            float cc = 0.f;
#pragma unroll
            for (int u = 0; u < 8; u++) cc += wv[u] * b2[u * NC_ + c];
            out[row * NC_ + c] = s[j] + cc;
        }
    }
}

// ---------------------------------------------------------------------------
extern "C" void kernel_launch(void* const* d_in, const int* in_sizes, int n_in,
                              void* d_out, int out_size, void* d_ws, size_t ws_size,
                              hipStream_t stream)
{
    const float* x  = (const float*)d_in[0];
    const float* p1 = (const float*)d_in[1];
    const float* p2 = (const float*)d_in[2];
    const float* pf = (const float*)d_in[3];
    const float* W0 = (const float*)d_in[4];
    const float* b0 = (const float*)d_in[5];
    const float* W1 = (const float*)d_in[6];
    const float* b1 = (const float*)d_in[7];
    const float* W2 = (const float*)d_in[8];
    const float* b2 = (const float*)d_in[9];
    float* out = (float*)d_out;

    char* ws = (char*)d_ws;
    size_t off = 0;
    auto alloc = [&](size_t bytes) -> void* {
        void* p = ws + off;
        off += (bytes + 255) & ~(size_t)255;
        return p;
    };
    unsigned short* W0r   = (unsigned short*)alloc((size_t)4096 * 512 * 2);
    unsigned short* W1t   = (unsigned short*)alloc((size_t)U_ * 512 * 512 * 2);
    unsigned short* Woutt = (unsigned short*)alloc((size_t)64 * 4096 * 2);
    unsigned short* xb    = (unsigned short*)alloc((size_t)B_ * 512 * 2);

    // a1 planar (8 x Bc x 512 bf16) + fp32 partial (8 x Bc x 64). No h1.
    size_t remain = ws_size > off ? ws_size - off : 0;
    int Bc = 2048;
    for (int cand = B_; cand >= 2048; cand >>= 1) {
        size_t need = 8ull * cand * 512 * 2 + 8ull * cand * 64 * 4 + 1024;
        if (need <= remain) { Bc = cand; break; }
    }
    unsigned short* a1 = (unsigned short*)alloc(8ull * Bc * 512 * 2);
    float* partial     = (float*)alloc(8ull * Bc * 64 * 4);

    prep_all<<<dim3(9216), 256, 0, stream>>>(
        p2, pf, W0, W1, W2, x, W0r, W1t, Woutt, xb);

    const int Mb = Bc / 128;
    const long plane = (long)Bc * 512;
    for (int bb = 0; bb < B_; bb += Bc) {
        gemm0_mix<<<dim3(16 * Mb), 256, 0, stream>>>(
            xb + (long)bb * 512, W0r, b0, p1, a1, plane);
        gemm_hout<<<dim3(8 * (Bc / 64)), 256, 0, stream>>>(
            a1, W1t, b1, Woutt, partial, plane);
        reduce_out<<<dim3(Bc / 64), 256, 0, stream>>>(
            partial, pf, b2, out + (long)bb * NC_, Bc);
    }
}